// Round 8
// baseline (166.277 us; speedup 1.0000x reference)
//
#include <hip/hip_runtime.h>
#include <cmath>

#define FIN 256
#define FQK 256
#define SCALING 0.0625f  // FQK^-0.5 = 1/16
#define MAX_SEG 256
#define NCHUNK 4         // 64 k-cols per chunk: 20000*64*2B = 2.56 MB slice, fits 4MiB XCD L2

typedef __bf16 bf16_t;
typedef bf16_t bf16x8 __attribute__((ext_vector_type(8)));
typedef float  f32x4  __attribute__((ext_vector_type(4)));

__device__ __forceinline__ unsigned short f2bf(float f) {
    unsigned int u = __float_as_uint(f);
    u += 0x7FFFu + ((u >> 16) & 1u);   // RNE
    return (unsigned short)(u >> 16);
}
__device__ __forceinline__ float bf_lo(unsigned int w) { return __uint_as_float(w << 16); }
__device__ __forceinline__ float bf_hi(unsigned int w) { return __uint_as_float(w & 0xFFFF0000u); }
__device__ __forceinline__ unsigned int pack2(float a, float b) {
    return (unsigned int)f2bf(a) | ((unsigned int)f2bf(b) << 16);
}

// ---------------------------------------------------------------------------
// Kernel 1 (fused): blocks [0,128) convert W -> bf16 Wb; blocks [128, ...)
// compute seg[n] = lower_bound(src, n). One dispatch instead of two.
// ---------------------------------------------------------------------------
__global__ __launch_bounds__(256) void prep_kernel(const float* __restrict__ W,
                                                   uint2* __restrict__ Wb2,
                                                   const int* __restrict__ src,
                                                   int* __restrict__ seg, int N, int E) {
    const int b = blockIdx.x;
    if (b < 128) {
        const int i = b * 256 + threadIdx.x;            // 4-float group
        const float4 v = ((const float4*)W)[i];
        uint2 p;
        p.x = pack2(v.x, v.y);
        p.y = pack2(v.z, v.w);
        Wb2[i] = p;
    } else {
        const int n = (b - 128) * 256 + threadIdx.x;
        if (n <= N) {
            int lo = 0, hi = E;
            while (lo < hi) {
                const int mid = (lo + hi) >> 1;
                if (src[mid] < n) lo = mid + 1; else hi = mid;
            }
            seg[n] = lo;
        }
    }
}

// ---------------------------------------------------------------------------
// Kernel 2: qk projection. h=blockIdx.y: 0->q (scaled), 1->k.
// One barrier total; A-frags hoisted to regs (64 VGPR), B loaded per-ft
// (32 transient VGPR) from L2-resident Wb -> ~150 VGPR, 3 waves/SIMD.
// ---------------------------------------------------------------------------
#define GROWS    32
#define SAROW    264   // shorts per LDS row; b128 reads land 2-way (free) banks

__global__ __launch_bounds__(256) void gemm_qk_kernel(const float* __restrict__ x,
                                                      const unsigned short* __restrict__ Wb,
                                                      unsigned short* __restrict__ qarr,
                                                      unsigned short* __restrict__ karr,
                                                      int N) {
    __shared__ unsigned short sA[GROWS * SAROW];

    const int h    = blockIdx.y;
    const unsigned short* __restrict__ Wbh = Wb + (size_t)h * FQK * FIN;
    unsigned short* __restrict__ outp = h ? karr : qarr;
    const float scale = h ? 1.0f : SCALING;

    const int t    = threadIdx.x;
    const int wv   = t >> 6;
    const int lane = t & 63;
    const int q    = lane >> 4;
    const int m16  = lane & 15;
    const int n0   = blockIdx.x * GROWS;
    const int f0   = wv * 64;

    // ---- A stage: full 32x256 tile fp32->bf16, 8 float4 loads/thread
    {
        const int r  = t >> 6;
        const int c4 = (t & 63) * 4;
#pragma unroll
        for (int u = 0; u < 8; ++u) {
            const int row = u * 4 + r;
            const int n = n0 + row;
            float4 v = make_float4(0.f, 0.f, 0.f, 0.f);
            if (n < N) v = *(const float4*)(x + (size_t)n * FIN + c4);
            uint2 p;
            p.x = pack2(v.x, v.y);
            p.y = pack2(v.z, v.w);
            *(uint2*)&sA[row * SAROW + c4] = p;
        }
    }
    __syncthreads();   // the only barrier

    // ---- hoist all A-frags: 2 mt x 8 kc x 4 VGPR = 64 VGPR
    bf16x8 afrag[2][8];
#pragma unroll
    for (int mt = 0; mt < 2; ++mt)
#pragma unroll
        for (int kc = 0; kc < 8; ++kc)
            afrag[mt][kc] = *(const bf16x8*)&sA[(mt * 16 + m16) * SAROW + kc * 32 + q * 8];

    f32x4 acc[2][4] = {};
#pragma unroll
    for (int ft = 0; ft < 4; ++ft) {
        const uint4* __restrict__ brow =
            (const uint4*)(Wbh + (size_t)(f0 + ft * 16 + m16) * FIN);
        uint4 bfr[8];
#pragma unroll
        for (int kc = 0; kc < 8; ++kc) bfr[kc] = brow[kc * 4 + q];
#pragma unroll
        for (int kc = 0; kc < 8; ++kc) {
            union { uint4 u; bf16x8 v; } bu;
            bu.u = bfr[kc];
#pragma unroll
            for (int mt = 0; mt < 2; ++mt)
                acc[mt][ft] = __builtin_amdgcn_mfma_f32_16x16x32_bf16(afrag[mt][kc], bu.v,
                                                                     acc[mt][ft], 0, 0, 0);
        }
    }

    // ---- store: within 16x16 tile, col = m16 (f), row = q*4 + r (n)
#pragma unroll
    for (int mt = 0; mt < 2; ++mt) {
#pragma unroll
        for (int r = 0; r < 4; ++r) {
            const int n = n0 + mt * 16 + q * 4 + r;
            if (n < N) {
#pragma unroll
                for (int ft = 0; ft < 4; ++ft)
                    outp[(size_t)n * FIN + f0 + ft * 16 + m16] = f2bf(acc[mt][ft][r] * scale);
            }
        }
    }
}

// ---------------------------------------------------------------------------
// Kernel 3: chunked partial dots. blockIdx.y = chunk c (64 k-cols); dispatch
// order runs all nodes for c=0 first -> concurrent cohort hits one 2.56 MB
// k-slice (L2-resident). Wave per node; 4 slots x 16 sublanes; 16 edges/iter
// (x4 unroll, 4 independent uint2 gathers in flight/lane).
// pdot[c][e] = partial dot (fp32), staged via LDS, flushed coalesced.
// ---------------------------------------------------------------------------
__global__ __launch_bounds__(256) void chunk_dot_kernel(const unsigned short* __restrict__ qarr,
                                                        const unsigned short* __restrict__ karr,
                                                        const int* __restrict__ dest,
                                                        const int* __restrict__ seg,
                                                        float* __restrict__ pdot,
                                                        int N, int E) {
    __shared__ float plds[4][MAX_SEG];

    const int c    = blockIdx.y;
    const int w    = threadIdx.x >> 6;
    const int lane = threadIdx.x & 63;
    const int n    = blockIdx.x * 4 + w;
    const int g    = lane >> 4;   // slot 0..3
    const int j    = lane & 15;   // sublane 0..15

    int s0 = 0, cnt = 0;
    if (n < N) {
        s0 = seg[n];
        cnt = seg[n + 1] - s0;
    }
    if (cnt <= 0) return;   // no cross-wave LDS sharing -> no barrier needed

    // q chunk: 4 bf16 per sublane
    const uint2 qc = ((const uint2*)(qarr + (size_t)n * FIN))[c * 16 + j];
    const float qx0 = bf_lo(qc.x), qx1 = bf_hi(qc.x);
    const float qx2 = bf_lo(qc.y), qx3 = bf_hi(qc.y);

    for (int base = 0; base < cnt; base += 64) {
        const int m = min(64, cnt - base);
        const int vd = (lane < m) ? dest[s0 + base + lane] : 0;
        const int nit = (m + 15) >> 4;
        for (int it = 0; it < nit; ++it) {
            const int e0 = it * 16 + g * 4;
            int dd[4];
#pragma unroll
            for (int u = 0; u < 4; ++u) dd[u] = __shfl(vd, e0 + u, 64);
            uint2 kv[4];
#pragma unroll
            for (int u = 0; u < 4; ++u)
                kv[u] = ((const uint2*)(karr +
                          (size_t)((e0 + u < m) ? dd[u] : 0) * FIN))[c * 16 + j];
            float dot[4];
#pragma unroll
            for (int u = 0; u < 4; ++u)
                dot[u] = bf_lo(kv[u].x) * qx0 + bf_hi(kv[u].x) * qx1
                       + bf_lo(kv[u].y) * qx2 + bf_hi(kv[u].y) * qx3;
            // interleaved butterflies over the 16 sublanes
#pragma unroll
            for (int st = 1; st <= 8; st <<= 1) {
#pragma unroll
                for (int u = 0; u < 4; ++u)
                    dot[u] += __shfl_xor(dot[u], st, 64);
            }
            if (j == 0) {
#pragma unroll
                for (int u = 0; u < 4; ++u) {
                    const int idx = base + e0 + u;
                    if (e0 + u < m && idx < MAX_SEG) plds[w][idx] = dot[u];
                }
            }
        }
    }

    // flush partials coalesced
    float* __restrict__ pc = pdot + (size_t)c * E;
    const int lim = cnt < MAX_SEG ? cnt : MAX_SEG;
    for (int i = lane; i < lim; i += 64) pc[s0 + i] = plds[w][i];
}

// ---------------------------------------------------------------------------
// Kernel 4: finalize. Wave per node: aw = sum of 4 partials, exp, 6-step
// butterfly segment-sum, normalize in place.
// ---------------------------------------------------------------------------
__global__ __launch_bounds__(256) void finalize_kernel(const float* __restrict__ pdot,
                                                       const int* __restrict__ seg,
                                                       float* __restrict__ out,
                                                       int N, int E) {
    const int w    = threadIdx.x >> 6;
    const int lane = threadIdx.x & 63;
    const int n    = blockIdx.x * 4 + w;
    if (n >= N) return;
    const int s0  = seg[n];
    const int cnt = seg[n + 1] - s0;
    if (cnt <= 0) return;

    float sum = 0.f;
    for (int i = lane; i < cnt; i += 64) {
        const size_t e = (size_t)(s0 + i);
        const float aw = pdot[e] + pdot[(size_t)E + e]
                       + pdot[2 * (size_t)E + e] + pdot[3 * (size_t)E + e];
        const float ex = __expf(aw);
        out[e] = ex;
        sum += ex;
    }
#pragma unroll
    for (int st = 1; st <= 32; st <<= 1) sum += __shfl_xor(sum, st, 64);
    const float inv = 1.0f / sum;
    for (int i = lane; i < cnt; i += 64) out[s0 + i] *= inv;   // same-lane RMW
}

// ---------------------------------------------------------------------------
extern "C" void kernel_launch(void* const* d_in, const int* in_sizes, int n_in,
                              void* d_out, int out_size, void* d_ws, size_t ws_size,
                              hipStream_t stream) {
    const float* x  = (const float*)d_in[0];
    const int*   ei = (const int*)d_in[1];   // src = ei[0:E], dest = ei[E:2E]
    const float* W  = (const float*)d_in[2];
    float* out = (float*)d_out;

    const int N = in_sizes[0] / FIN;
    const int E = in_sizes[1] / 2;

    // workspace layout (16B-aligned segments)
    unsigned short* qarr = (unsigned short*)d_ws;              // N*256 bf16
    unsigned short* karr = qarr + (size_t)N * FIN;             // N*256 bf16
    unsigned short* Wb   = karr + (size_t)N * FIN;             // 512*256 bf16
    float*          pdot = (float*)(Wb + (size_t)2 * FQK * FIN); // 4*E fp32
    int*            seg  = (int*)(pdot + (size_t)NCHUNK * E);  // N+1

    prep_kernel<<<128 + (N + 256) / 256, 256, 0, stream>>>(W, (uint2*)Wb, ei, seg, N, E);

    dim3 ggrid((N + GROWS - 1) / GROWS, 2);
    gemm_qk_kernel<<<ggrid, 256, 0, stream>>>(x, Wb, qarr, karr, N);

    dim3 cgrid((N + 3) / 4, NCHUNK);
    chunk_dot_kernel<<<cgrid, 256, 0, stream>>>(qarr, karr, ei + E, seg, pdot, N, E);

    finalize_kernel<<<(N + 3) / 4, 256, 0, stream>>>(pdot, seg, out, N, E);
}